// Round 1
// baseline (3533.239 us; speedup 1.0000x reference)
//
#include <hip/hip_runtime.h>
#include <hip/hip_bf16.h>

#define N_NODES 20000
#define N_EDGES 320000
#define BATCH   64
#define N_IN    128
#define N_OUT   256
#define CAP     64
#define ITERS   150
#define LEAK    0.01f

// ---------------------------------------------------------------------------
// Kernel 1: init h0 = 0, b_in = bias, cnt = 0
// ---------------------------------------------------------------------------
__global__ void init_kernel(float* __restrict__ h0, float* __restrict__ bin,
                            int* __restrict__ cnt, const float* __restrict__ biases) {
    int idx = blockIdx.x * blockDim.x + threadIdx.x;
    int total = N_NODES * BATCH;
    for (int i = idx; i < total; i += gridDim.x * blockDim.x) {
        h0[i] = 0.0f;
        bin[i] = biases[i >> 6];   // bias per node, broadcast over batch
    }
    for (int i = idx; i < N_NODES; i += gridDim.x * blockDim.x) {
        cnt[i] = 0;
    }
}

// ---------------------------------------------------------------------------
// Kernel 2: input scatter  b_in[in_idx[i]][b] = bias + in_w[i]*x[b][i]
// last-occurrence-wins to match .at[].set semantics with duplicate indices
// ---------------------------------------------------------------------------
__global__ void input_scatter_kernel(float* __restrict__ bin,
                                     const float* __restrict__ x,
                                     const float* __restrict__ in_w,
                                     const int* __restrict__ in_idx,
                                     const float* __restrict__ biases) {
    int i = blockIdx.x;      // input channel 0..127
    int b = threadIdx.x;     // batch lane 0..63
    int node = in_idx[i];
    // skip if a later input writes the same node (last write wins)
    for (int j = i + 1; j < N_IN; j++)
        if (in_idx[j] == node) return;
    bin[node * BATCH + b] = biases[node] + in_w[i] * x[b * N_IN + i];
}

// ---------------------------------------------------------------------------
// Kernel 3: COO -> ELL build (atomic slot assignment; order within a row is
// non-deterministic but only perturbs FP sum order by ~1e-7, far below tol)
// ---------------------------------------------------------------------------
__global__ void ell_build_kernel(const int* __restrict__ rows,
                                 const int* __restrict__ cols,
                                 const float* __restrict__ rec_w,
                                 int* __restrict__ ellc, float* __restrict__ ellw,
                                 int* __restrict__ cnt) {
    int e = blockIdx.x * blockDim.x + threadIdx.x;
    if (e >= N_EDGES) return;
    int r = rows[e];
    int s = atomicAdd(&cnt[r], 1);
    if (s < CAP) {
        ellc[r * CAP + s] = cols[e];
        ellw[r * CAP + s] = rec_w[e];
    }
}

// ---------------------------------------------------------------------------
// Kernel 4: fused SpMV + activation.  One wave per node; lane = batch index.
// h layout [node][64] -> each edge is one coalesced 256B load.
// Edge meta held in registers, broadcast by __shfl.
// ---------------------------------------------------------------------------
__global__ __launch_bounds__(256) void spmv_act_kernel(
        const float* __restrict__ h_in, float* __restrict__ h_out,
        const float* __restrict__ bin,
        const int* __restrict__ ellc, const float* __restrict__ ellw,
        const int* __restrict__ cnt) {
    int wave = threadIdx.x >> 6;          // 0..3
    int lane = threadIdx.x & 63;          // batch index
    int node = blockIdx.x * 4 + wave;
    if (node >= N_NODES) return;

    int c = cnt[node];
    if (c > CAP) c = CAP;

    float acc = bin[node * BATCH + lane];

    // each lane holds edge-slot `lane`'s metadata; broadcast per-k via shfl
    int   mycol = ellc[node * CAP + lane];
    float myw   = ellw[node * CAP + lane];

    for (int k = 0; k < c; k++) {
        int   col = __shfl(mycol, k);
        float w   = __shfl(myw,   k);
        acc += w * h_in[col * BATCH + lane];
    }

    // mml activation: leak below 0, Michaelis-Menten saturation above 0.5
    float u = (acc < 0.0f) ? acc * LEAK : acc;
    h_out[node * BATCH + lane] = (u > 0.5f) ? (1.0f - 0.25f / u) : u;
}

// ---------------------------------------------------------------------------
// Kernel 5: output gather  out[b][o] = out_w[o] * h[out_idx[o]][b]
// ---------------------------------------------------------------------------
__global__ void output_kernel(const float* __restrict__ h,
                              const int* __restrict__ out_idx,
                              const float* __restrict__ out_w,
                              float* __restrict__ out) {
    int o = threadIdx.x;   // 0..255
    int b = blockIdx.x;    // 0..63
    out[b * N_OUT + o] = out_w[o] * h[out_idx[o] * BATCH + b];
}

// ---------------------------------------------------------------------------
extern "C" void kernel_launch(void* const* d_in, const int* in_sizes, int n_in,
                              void* d_out, int out_size, void* d_ws, size_t ws_size,
                              hipStream_t stream) {
    const float* x      = (const float*)d_in[0];
    const float* in_w   = (const float*)d_in[1];
    const float* out_w  = (const float*)d_in[2];
    const float* rec_w  = (const float*)d_in[3];
    const float* biases = (const float*)d_in[4];
    const int*   rows   = (const int*)d_in[5];
    const int*   cols   = (const int*)d_in[6];
    const int*   in_idx = (const int*)d_in[7];
    const int*   oidx   = (const int*)d_in[8];
    float* out = (float*)d_out;

    // workspace layout (all rebuilt every call; harness does not re-poison)
    char* ws = (char*)d_ws;
    float* h0   = (float*)ws;                       ws += (size_t)N_NODES * BATCH * 4;
    float* h1   = (float*)ws;                       ws += (size_t)N_NODES * BATCH * 4;
    float* bin  = (float*)ws;                       ws += (size_t)N_NODES * BATCH * 4;
    float* ellw = (float*)ws;                       ws += (size_t)N_NODES * CAP * 4;
    int*   ellc = (int*)ws;                         ws += (size_t)N_NODES * CAP * 4;
    int*   cnt  = (int*)ws;                         ws += (size_t)N_NODES * 4;

    // 1. init
    init_kernel<<<1024, 256, 0, stream>>>(h0, bin, cnt, biases);
    // 2. input scatter
    input_scatter_kernel<<<N_IN, BATCH, 0, stream>>>(bin, x, in_w, in_idx, biases);
    // 3. ELL build
    ell_build_kernel<<<(N_EDGES + 255) / 256, 256, 0, stream>>>(rows, cols, rec_w,
                                                                ellc, ellw, cnt);
    // 4. recurrent iterations (ping-pong)
    float* hA = h0;
    float* hB = h1;
    for (int t = 0; t < ITERS; t++) {
        spmv_act_kernel<<<N_NODES / 4, 256, 0, stream>>>(hA, hB, bin, ellc, ellw, cnt);
        float* tmp = hA; hA = hB; hB = tmp;
    }
    // 5. output gather (hA = last written buffer)
    output_kernel<<<BATCH, N_OUT, 0, stream>>>(hA, oidx, out_w, out);
}